// Round 2
// baseline (401.324 us; speedup 1.0000x reference)
//
#include <hip/hip_runtime.h>
#include <hip/hip_bf16.h>

typedef __attribute__((ext_vector_type(8))) short short8;
typedef __attribute__((ext_vector_type(4))) float f32x4;
typedef __hip_bfloat16 bf16_t;

#define SEQ 2048
#define DM 1024
#define NH 16
#define DK 64

static __device__ __forceinline__ f32x4 mfma16x16x32(short8 a, short8 b, f32x4 c) {
  return __builtin_amdgcn_mfma_f32_16x16x32_bf16(a, b, c, 0, 0, 0);
}

// ---------------- dtype sniffer: flag=1 if buffers are bf16, 0 if fp32 ------
// Under bf16, the low 16 bits of each 32-bit word are a real bf16 value of
// N(0,1) data -> exponent field in a sane range. Under fp32 those bits are
// mantissa bits -> uniform random exponent field.
__global__ void sniff_dtype(const unsigned int* __restrict__ x, int* __restrict__ flag) {
  int lane = threadIdx.x & 63;
  int cnt = 0;
  for (int r = 0; r < 4; ++r) {
    unsigned int v = x[lane + r * 64];
    int e = (v >> 7) & 0xFF;
    if (e >= 100 && e <= 145) cnt++;
  }
  for (int d = 1; d < 64; d <<= 1) cnt += __shfl_xor(cnt, d, 64);
  if (lane == 0) *flag = (cnt >= 192) ? 1 : 0;
}

// ---------------- canonicalize x to bf16 ----------------
__global__ __launch_bounds__(256) void convert_x(const void* __restrict__ src,
                                                 bf16_t* __restrict__ dst,
                                                 const int* __restrict__ flag, int n4) {
  int f = *flag;
  int i = blockIdx.x * blockDim.x + threadIdx.x;
  if (i >= n4) return;
  if (f) {
    ((uint2*)dst)[i] = ((const uint2*)src)[i];
  } else {
    const float4 v = ((const float4*)src)[i];
    bf16_t o[4] = {__float2bfloat16(v.x), __float2bfloat16(v.y),
                   __float2bfloat16(v.z), __float2bfloat16(v.w)};
    ((uint2*)dst)[i] = *(const uint2*)o;
  }
}

// ---------------- transpose W (1024x1024) -> WT[n][k], dtype-dispatched -----
__global__ __launch_bounds__(256) void transpose_w(const void* __restrict__ w0,
                                                   const void* __restrict__ w1,
                                                   const void* __restrict__ w2,
                                                   const void* __restrict__ w3,
                                                   bf16_t* __restrict__ wt_base,
                                                   const int* __restrict__ flag) {
  int f = *flag;
  const void* src = (blockIdx.z == 0) ? w0 : (blockIdx.z == 1) ? w1
                  : (blockIdx.z == 2) ? w2 : w3;
  bf16_t* dst = wt_base + (size_t)blockIdx.z * DM * DM;
  __shared__ bf16_t tile[64][65];
  int t = threadIdx.x;
  int tx = t & 63, ty = t >> 6;
  int r0 = blockIdx.y * 64, c0 = blockIdx.x * 64;
  for (int i = 0; i < 64; i += 4) {
    size_t idx = (size_t)(r0 + ty + i) * DM + c0 + tx;
    tile[ty + i][tx] = f ? ((const bf16_t*)src)[idx]
                         : __float2bfloat16(((const float*)src)[idx]);
  }
  __syncthreads();
  for (int i = 0; i < 64; i += 4)
    dst[(size_t)(c0 + ty + i) * DM + r0 + tx] = tile[tx][ty + i];
}

// ---------------- GEMM: C = A(4096x1024) @ B(1024x1024), B given as BT[n][k]
// mode 0: store row-major [4096][1024] to out (dtype per flag)
// mode 1: store [B,NH,SEQ,DK] bf16 with RoPE
// mode 2: store [B,NH,SEQ,DK] bf16 plain
__global__ __launch_bounds__(256) void gemm_qkv(const bf16_t* __restrict__ A,
                                                const bf16_t* __restrict__ BT,
                                                void* __restrict__ out,
                                                const int* __restrict__ tokpos,
                                                const int* __restrict__ flag,
                                                int mode) {
  __shared__ __align__(16) bf16_t As[64][40];
  __shared__ __align__(16) bf16_t Bs[64][40];
  int f = *flag;
  int t = threadIdx.x;
  int w = t >> 6, lane = t & 63, l15 = lane & 15, quad = lane >> 4;
  int m0 = blockIdx.y * 64, n0 = blockIdx.x * 64;
  int lr = t >> 2, lc = (t & 3) * 8;
  f32x4 acc[4] = {};
  for (int kk = 0; kk < DM; kk += 32) {
    *(short8*)&As[lr][lc] = *(const short8*)&A[(size_t)(m0 + lr) * DM + kk + lc];
    *(short8*)&Bs[lr][lc] = *(const short8*)&BT[(size_t)(n0 + lr) * DM + kk + lc];
    __syncthreads();
    short8 af = *(const short8*)&As[w * 16 + l15][quad * 8];
#pragma unroll
    for (int nt = 0; nt < 4; ++nt) {
      short8 bfr = *(const short8*)&Bs[nt * 16 + l15][quad * 8];
      acc[nt] = mfma16x16x32(af, bfr, acc[nt]);
    }
    __syncthreads();
  }
#pragma unroll
  for (int nt = 0; nt < 4; ++nt) {
    int col = n0 + nt * 16 + l15;
#pragma unroll
    for (int reg = 0; reg < 4; ++reg) {
      int m = m0 + w * 16 + quad * 4 + reg;
      float v = acc[nt][reg];
      if (mode == 0) {
        size_t oidx = (size_t)m * DM + col;
        if (f) ((bf16_t*)out)[oidx] = __float2bfloat16(v);
        else   ((float*)out)[oidx] = v;
      } else {
        int b = m >> 11, s_idx = m & (SEQ - 1);
        int h = col >> 6, d = col & 63;
        size_t oidx = (((size_t)(b * NH + h)) * SEQ + s_idx) * DK + d;
        if (mode == 2) {
          ((bf16_t*)out)[oidx] = __float2bfloat16(v);
        } else {
          float part = __shfl_xor(v, 1, 64);
          int p = d >> 1;
          float invf = __powf(10000.0f, -(float)p * (1.0f / 32.0f));
          float ang = (float)tokpos[m] * invf;
          float sn, cs;
          sincosf(ang, &sn, &cs);
          float res = (d & 1) ? (part * sn + v * cs) : (v * cs - part * sn);
          ((bf16_t*)out)[oidx] = __float2bfloat16(res);
        }
      }
    }
  }
}

// ---------------- causal flash attention, D=64, BQ=64, BK=64 ----------------
__global__ __launch_bounds__(256) void attn_fwd(const bf16_t* __restrict__ Q,
                                                const bf16_t* __restrict__ K,
                                                const bf16_t* __restrict__ V,
                                                bf16_t* __restrict__ O) {
  int qb = blockIdx.x, bh = blockIdx.y;
  int b = bh >> 4, h = bh & 15;
  int t = threadIdx.x;
  int w = t >> 6, lane = t & 63, l15 = lane & 15, quad = lane >> 4;
  const size_t base = (size_t)bh * SEQ * DK;
  const bf16_t* Qp = Q + base;
  const bf16_t* Kp = K + base;
  const bf16_t* Vp = V + base;

  __shared__ __align__(16) bf16_t VT[64][72];      // V^T tile: [d][k]
  __shared__ __align__(16) bf16_t Pb[4][16][72];   // per-wave P buffer

  int qrow = qb * 64 + w * 16 + l15;
  short8 qf[2];
  qf[0] = *(const short8*)(Qp + (size_t)qrow * DK + quad * 8);
  qf[1] = *(const short8*)(Qp + (size_t)qrow * DK + 32 + quad * 8);

  f32x4 oacc[4] = {};
  float m_run[4], l_run[4];
#pragma unroll
  for (int r = 0; r < 4; ++r) { m_run[r] = -30000.0f; l_run[r] = 0.0f; }

  for (int kb = 0; kb <= qb; ++kb) {
#pragma unroll
    for (int r = 0; r < 2; ++r) {
      int idx = t + r * 256;
      int kk = idx >> 3, dg = (idx & 7) * 8;
      short8 vv = *(const short8*)(Vp + (size_t)(kb * 64 + kk) * DK + dg);
#pragma unroll
      for (int j = 0; j < 8; ++j) VT[dg + j][kk] = ((const bf16_t*)&vv)[j];
    }
    __syncthreads();

    f32x4 sc[4];
#pragma unroll
    for (int kt = 0; kt < 4; ++kt) {
      f32x4 a = {};
      const bf16_t* krow = Kp + (size_t)(kb * 64 + kt * 16 + l15) * DK;
      short8 kf0 = *(const short8*)(krow + quad * 8);
      short8 kf1 = *(const short8*)(krow + 32 + quad * 8);
      a = mfma16x16x32(qf[0], kf0, a);
      a = mfma16x16x32(qf[1], kf1, a);
      sc[kt] = a;
    }
#pragma unroll
    for (int kt = 0; kt < 4; ++kt)
#pragma unroll
      for (int reg = 0; reg < 4; ++reg) {
        float sv = sc[kt][reg] * 0.125f;
        if (kb == qb) {
          int kg = kt * 16 + l15;
          int qg = w * 16 + quad * 4 + reg;
          if (kg > qg) sv = -30000.0f;
        }
        sc[kt][reg] = sv;
      }
    float mx[4];
#pragma unroll
    for (int reg = 0; reg < 4; ++reg)
      mx[reg] = fmaxf(fmaxf(sc[0][reg], sc[1][reg]), fmaxf(sc[2][reg], sc[3][reg]));
    for (int d = 1; d < 16; d <<= 1)
#pragma unroll
      for (int reg = 0; reg < 4; ++reg)
        mx[reg] = fmaxf(mx[reg], __shfl_xor(mx[reg], d, 64));

    float alpha[4];
#pragma unroll
    for (int reg = 0; reg < 4; ++reg) {
      float mn = fmaxf(m_run[reg], mx[reg]);
      alpha[reg] = __expf(m_run[reg] - mn);
      m_run[reg] = mn;
    }
    float rs[4] = {0.f, 0.f, 0.f, 0.f};
#pragma unroll
    for (int kt = 0; kt < 4; ++kt)
#pragma unroll
      for (int reg = 0; reg < 4; ++reg) {
        float p = __expf(sc[kt][reg] - m_run[reg]);
        rs[reg] += p;
        Pb[w][quad * 4 + reg][kt * 16 + l15] = __float2bfloat16(p);
      }
    for (int d = 1; d < 16; d <<= 1)
#pragma unroll
      for (int reg = 0; reg < 4; ++reg)
        rs[reg] += __shfl_xor(rs[reg], d, 64);
#pragma unroll
    for (int reg = 0; reg < 4; ++reg)
      l_run[reg] = l_run[reg] * alpha[reg] + rs[reg];
#pragma unroll
    for (int dt = 0; dt < 4; ++dt)
#pragma unroll
      for (int reg = 0; reg < 4; ++reg)
        oacc[dt][reg] *= alpha[reg];

    short8 pf0 = *(const short8*)&Pb[w][l15][quad * 8];
    short8 pf1 = *(const short8*)&Pb[w][l15][32 + quad * 8];
#pragma unroll
    for (int dt = 0; dt < 4; ++dt) {
      short8 vf0 = *(const short8*)&VT[dt * 16 + l15][quad * 8];
      short8 vf1 = *(const short8*)&VT[dt * 16 + l15][32 + quad * 8];
      oacc[dt] = mfma16x16x32(pf0, vf0, oacc[dt]);
      oacc[dt] = mfma16x16x32(pf1, vf1, oacc[dt]);
    }
    __syncthreads();
  }

#pragma unroll
  for (int dt = 0; dt < 4; ++dt)
#pragma unroll
    for (int reg = 0; reg < 4; ++reg) {
      int q = qb * 64 + w * 16 + quad * 4 + reg;
      float v = oacc[dt][reg] / l_run[reg];
      O[((size_t)b * SEQ + q) * DM + h * DK + dt * 16 + l15] = __float2bfloat16(v);
    }
}

extern "C" void kernel_launch(void* const* d_in, const int* in_sizes, int n_in,
                              void* d_out, int out_size, void* d_ws, size_t ws_size,
                              hipStream_t stream) {
  const void* x = d_in[0];
  const int* tokpos = (const int*)d_in[1];
  const void* WQ = d_in[2];
  const void* WK = d_in[3];
  const void* WV = d_in[4];
  const void* WO = d_in[5];

  char* ws = (char*)d_ws;
  const size_t MB = 1024 * 1024;
  bf16_t* WT = (bf16_t*)ws;                    // 8 MB (4 x 1024x1024 bf16)
  bf16_t* Qb = (bf16_t*)(ws + 8 * MB);         // 8 MB
  bf16_t* Kb = (bf16_t*)(ws + 16 * MB);        // 8 MB
  bf16_t* Vb = (bf16_t*)(ws + 24 * MB);        // 8 MB
  bf16_t* Xc = (bf16_t*)(ws + 32 * MB);        // 8 MB (canonical bf16 x; reused as Ab)
  bf16_t* Ab = Xc;                             // attn out reuses Xc after last read
  int* flag  = (int*)(ws + 40 * MB);

  dim3 blk(256);
  sniff_dtype<<<1, 64, 0, stream>>>((const unsigned int*)x, flag);
  convert_x<<<4096, blk, 0, stream>>>(x, Xc, flag, (SEQ * 2 * DM) / 4);
  transpose_w<<<dim3(16, 16, 4), blk, 0, stream>>>(WQ, WK, WV, WO, WT, flag);
  gemm_qkv<<<dim3(16, 64), blk, 0, stream>>>(Xc, WT + (size_t)0 * DM * DM, Qb, tokpos, flag, 1);
  gemm_qkv<<<dim3(16, 64), blk, 0, stream>>>(Xc, WT + (size_t)1 * DM * DM, Kb, tokpos, flag, 1);
  gemm_qkv<<<dim3(16, 64), blk, 0, stream>>>(Xc, WT + (size_t)2 * DM * DM, Vb, tokpos, flag, 2);
  attn_fwd<<<dim3(32, 32), blk, 0, stream>>>(Qb, Kb, Vb, Ab);
  gemm_qkv<<<dim3(16, 64), blk, 0, stream>>>(Ab, WT + (size_t)3 * DM * DM, d_out, tokpos, flag, 0);
}

// Round 3
// 335.344 us; speedup vs baseline: 1.1968x; 1.1968x over previous
//
#include <hip/hip_runtime.h>
#include <hip/hip_bf16.h>

typedef __attribute__((ext_vector_type(8))) short short8;
typedef __attribute__((ext_vector_type(4))) float f32x4;
typedef __hip_bfloat16 bf16_t;

#define SEQ 2048
#define DM 1024
#define NH 16
#define DK 64

static __device__ __forceinline__ f32x4 mfma16x16x32(short8 a, short8 b, f32x4 c) {
  return __builtin_amdgcn_mfma_f32_16x16x32_bf16(a, b, c, 0, 0, 0);
}

// ---------------- dtype sniffer: flag=1 if buffers are bf16, 0 if fp32 ------
__global__ void sniff_dtype(const unsigned int* __restrict__ x, int* __restrict__ flag) {
  int lane = threadIdx.x & 63;
  int cnt = 0;
  for (int r = 0; r < 4; ++r) {
    unsigned int v = x[lane + r * 64];
    int e = (v >> 7) & 0xFF;
    if (e >= 100 && e <= 145) cnt++;
  }
  for (int d = 1; d < 64; d <<= 1) cnt += __shfl_xor(cnt, d, 64);
  if (lane == 0) *flag = (cnt >= 192) ? 1 : 0;
}

// ---------------- canonicalize x to bf16 ----------------
__global__ __launch_bounds__(256) void convert_x(const void* __restrict__ src,
                                                 bf16_t* __restrict__ dst,
                                                 const int* __restrict__ flag, int n4) {
  int f = *flag;
  int i = blockIdx.x * blockDim.x + threadIdx.x;
  if (i >= n4) return;
  if (f) {
    ((uint2*)dst)[i] = ((const uint2*)src)[i];
  } else {
    const float4 v = ((const float4*)src)[i];
    bf16_t o[4] = {__float2bfloat16(v.x), __float2bfloat16(v.y),
                   __float2bfloat16(v.z), __float2bfloat16(v.w)};
    ((uint2*)dst)[i] = *(const uint2*)o;
  }
}

// ---------------- transpose W (1024x1024) -> WT[n][k], dtype-dispatched -----
__global__ __launch_bounds__(256) void transpose_w(const void* __restrict__ w0,
                                                   const void* __restrict__ w1,
                                                   const void* __restrict__ w2,
                                                   const void* __restrict__ w3,
                                                   bf16_t* __restrict__ wt_base,
                                                   const int* __restrict__ flag) {
  int f = *flag;
  const void* src = (blockIdx.z == 0) ? w0 : (blockIdx.z == 1) ? w1
                  : (blockIdx.z == 2) ? w2 : w3;
  bf16_t* dst = wt_base + (size_t)blockIdx.z * DM * DM;
  __shared__ bf16_t tile[64][65];
  int t = threadIdx.x;
  int tx = t & 63, ty = t >> 6;
  int r0 = blockIdx.y * 64, c0 = blockIdx.x * 64;
  for (int i = 0; i < 64; i += 4) {
    size_t idx = (size_t)(r0 + ty + i) * DM + c0 + tx;
    tile[ty + i][tx] = f ? ((const bf16_t*)src)[idx]
                         : __float2bfloat16(((const float*)src)[idx]);
  }
  __syncthreads();
  for (int i = 0; i < 64; i += 4)
    dst[(size_t)(c0 + ty + i) * DM + r0 + tx] = tile[tx][ty + i];
}

// ---------------- fused QKV GEMM ----------------
// A (4096x1024) @ {WTq,WTk,WTv}^T. Q,K -> [B,NH,SEQ,DK] with RoPE.
// V -> transposed [B*NH, DK, SEQ] so attention can load B-frags directly.
__global__ __launch_bounds__(256) void gemm_qkv_fused(const bf16_t* __restrict__ A,
                                                      const bf16_t* __restrict__ WTq,
                                                      const bf16_t* __restrict__ WTk,
                                                      const bf16_t* __restrict__ WTv,
                                                      bf16_t* __restrict__ Qo,
                                                      bf16_t* __restrict__ Ko,
                                                      bf16_t* __restrict__ VTo,
                                                      const int* __restrict__ tokpos) {
  __shared__ __align__(16) bf16_t As[64][40];
  __shared__ __align__(16) bf16_t Bq[64][40];
  __shared__ __align__(16) bf16_t Bk[64][40];
  __shared__ __align__(16) bf16_t Bv[64][40];
  int t = threadIdx.x;
  int w = t >> 6, lane = t & 63, l15 = lane & 15, quad = lane >> 4;
  int m0 = blockIdx.y * 64, n0 = blockIdx.x * 64;
  int lr = t >> 2, lc = (t & 3) * 8;
  f32x4 accq[4] = {}, acck[4] = {}, accv[4] = {};
  for (int kk = 0; kk < DM; kk += 32) {
    *(short8*)&As[lr][lc] = *(const short8*)&A[(size_t)(m0 + lr) * DM + kk + lc];
    *(short8*)&Bq[lr][lc] = *(const short8*)&WTq[(size_t)(n0 + lr) * DM + kk + lc];
    *(short8*)&Bk[lr][lc] = *(const short8*)&WTk[(size_t)(n0 + lr) * DM + kk + lc];
    *(short8*)&Bv[lr][lc] = *(const short8*)&WTv[(size_t)(n0 + lr) * DM + kk + lc];
    __syncthreads();
    short8 af = *(const short8*)&As[w * 16 + l15][quad * 8];
#pragma unroll
    for (int nt = 0; nt < 4; ++nt) {
      accq[nt] = mfma16x16x32(af, *(const short8*)&Bq[nt * 16 + l15][quad * 8], accq[nt]);
      acck[nt] = mfma16x16x32(af, *(const short8*)&Bk[nt * 16 + l15][quad * 8], acck[nt]);
      accv[nt] = mfma16x16x32(af, *(const short8*)&Bv[nt * 16 + l15][quad * 8], accv[nt]);
    }
    __syncthreads();
  }
#pragma unroll
  for (int nt = 0; nt < 4; ++nt) {
    int col = n0 + nt * 16 + l15;
    int h = col >> 6, d = col & 63;
#pragma unroll
    for (int reg = 0; reg < 4; ++reg) {
      int m = m0 + w * 16 + quad * 4 + reg;
      int b = m >> 11, s_idx = m & (SEQ - 1);
      size_t bh = (size_t)(b * NH + h);
      float vq = accq[nt][reg], vk = acck[nt][reg], vv = accv[nt][reg];
      float pq = __shfl_xor(vq, 1, 64), pk = __shfl_xor(vk, 1, 64);
      int p = d >> 1;
      float invf = __powf(10000.0f, -(float)p * (1.0f / 32.0f));
      float ang = (float)tokpos[m] * invf;
      float sn, cs;
      sincosf(ang, &sn, &cs);
      float rq = (d & 1) ? (pq * sn + vq * cs) : (vq * cs - pq * sn);
      float rk = (d & 1) ? (pk * sn + vk * cs) : (vk * cs - pk * sn);
      size_t oidx = (bh * SEQ + s_idx) * DK + d;
      Qo[oidx] = __float2bfloat16(rq);
      Ko[oidx] = __float2bfloat16(rk);
      VTo[(bh * DK + d) * SEQ + s_idx] = __float2bfloat16(vv);
    }
  }
}

// ---------------- out-proj GEMM (mode 0 of the old generic kernel) ----------
__global__ __launch_bounds__(256) void gemm_out(const bf16_t* __restrict__ A,
                                                const bf16_t* __restrict__ BT,
                                                void* __restrict__ out,
                                                const int* __restrict__ flag) {
  __shared__ __align__(16) bf16_t As[64][40];
  __shared__ __align__(16) bf16_t Bs[64][40];
  int f = *flag;
  int t = threadIdx.x;
  int w = t >> 6, lane = t & 63, l15 = lane & 15, quad = lane >> 4;
  int m0 = blockIdx.y * 64, n0 = blockIdx.x * 64;
  int lr = t >> 2, lc = (t & 3) * 8;
  f32x4 acc[4] = {};
  for (int kk = 0; kk < DM; kk += 32) {
    *(short8*)&As[lr][lc] = *(const short8*)&A[(size_t)(m0 + lr) * DM + kk + lc];
    *(short8*)&Bs[lr][lc] = *(const short8*)&BT[(size_t)(n0 + lr) * DM + kk + lc];
    __syncthreads();
    short8 af = *(const short8*)&As[w * 16 + l15][quad * 8];
#pragma unroll
    for (int nt = 0; nt < 4; ++nt)
      acc[nt] = mfma16x16x32(af, *(const short8*)&Bs[nt * 16 + l15][quad * 8], acc[nt]);
    __syncthreads();
  }
#pragma unroll
  for (int nt = 0; nt < 4; ++nt) {
    int col = n0 + nt * 16 + l15;
#pragma unroll
    for (int reg = 0; reg < 4; ++reg) {
      int m = m0 + w * 16 + quad * 4 + reg;
      size_t oidx = (size_t)m * DM + col;
      if (f) ((bf16_t*)out)[oidx] = __float2bfloat16(acc[nt][reg]);
      else   ((float*)out)[oidx] = acc[nt][reg];
    }
  }
}

// ---------------- causal flash attention, balanced pairs, barrier-free ------
// Q,K: [B*NH, SEQ, DK]; VT: [B*NH, DK, SEQ]. Out: [B, SEQ, DM].
// Block (p, bh) handles q-tiles {p, 31-p}: exactly 33 KV-iterations each.
__global__ __launch_bounds__(256) void attn_fwd(const bf16_t* __restrict__ Q,
                                                const bf16_t* __restrict__ K,
                                                const bf16_t* __restrict__ VT,
                                                bf16_t* __restrict__ O) {
  int pidx = blockIdx.x, bh = blockIdx.y;
  int b = bh >> 4, h = bh & 15;
  int t = threadIdx.x;
  int w = t >> 6, lane = t & 63, l15 = lane & 15, quad = lane >> 4;
  const size_t base = (size_t)bh * SEQ * DK;
  const bf16_t* Qp = Q + base;
  const bf16_t* Kp = K + base;
  const bf16_t* VTp = VT + base;  // [DK][SEQ]

  __shared__ __align__(16) bf16_t Pb[4][16][72];  // per-wave P buffer

  for (int pass = 0; pass < 2; ++pass) {
    int qb = pass ? (31 - pidx) : pidx;

    int qrow = qb * 64 + w * 16 + l15;
    short8 qf0 = *(const short8*)(Qp + (size_t)qrow * DK + quad * 8);
    short8 qf1 = *(const short8*)(Qp + (size_t)qrow * DK + 32 + quad * 8);

    f32x4 oacc[4] = {};
    float m_run[4], l_run[4];
#pragma unroll
    for (int r = 0; r < 4; ++r) { m_run[r] = -30000.0f; l_run[r] = 0.0f; }

    short8 kf0[4], kf1[4], kn0[4], kn1[4], vf0[4], vf1[4];
#pragma unroll
    for (int kt = 0; kt < 4; ++kt) {
      const bf16_t* kr = Kp + (size_t)(kt * 16 + l15) * DK;
      kf0[kt] = *(const short8*)(kr + quad * 8);
      kf1[kt] = *(const short8*)(kr + 32 + quad * 8);
    }

    for (int kb = 0; kb <= qb; ++kb) {
      // V frags for current kb (needed only after softmax -> latency hidden)
#pragma unroll
      for (int dt = 0; dt < 4; ++dt) {
        const bf16_t* vr = VTp + (size_t)(dt * 16 + l15) * SEQ + kb * 64;
        vf0[dt] = *(const short8*)(vr + quad * 8);
        vf1[dt] = *(const short8*)(vr + 32 + quad * 8);
      }
      // S = Q K^T
      f32x4 sc[4];
#pragma unroll
      for (int kt = 0; kt < 4; ++kt) {
        f32x4 a = {};
        a = mfma16x16x32(qf0, kf0[kt], a);
        a = mfma16x16x32(qf1, kf1[kt], a);
        sc[kt] = a;
      }
      // prefetch K frags for kb+1
      if (kb < qb) {
#pragma unroll
        for (int kt = 0; kt < 4; ++kt) {
          const bf16_t* kr = Kp + (size_t)((kb + 1) * 64 + kt * 16 + l15) * DK;
          kn0[kt] = *(const short8*)(kr + quad * 8);
          kn1[kt] = *(const short8*)(kr + 32 + quad * 8);
        }
      }
      // scale + causal mask (diagonal tile only)
#pragma unroll
      for (int kt = 0; kt < 4; ++kt)
#pragma unroll
        for (int reg = 0; reg < 4; ++reg) {
          float sv = sc[kt][reg] * 0.125f;
          if (kb == qb) {
            int kg = kt * 16 + l15;
            int qg = w * 16 + quad * 4 + reg;
            if (kg > qg) sv = -30000.0f;
          }
          sc[kt][reg] = sv;
        }
      // row max
      float mx[4];
#pragma unroll
      for (int reg = 0; reg < 4; ++reg)
        mx[reg] = fmaxf(fmaxf(sc[0][reg], sc[1][reg]), fmaxf(sc[2][reg], sc[3][reg]));
      for (int d = 1; d < 16; d <<= 1)
#pragma unroll
        for (int reg = 0; reg < 4; ++reg)
          mx[reg] = fmaxf(mx[reg], __shfl_xor(mx[reg], d, 64));

      float alpha[4];
#pragma unroll
      for (int reg = 0; reg < 4; ++reg) {
        float mn = fmaxf(m_run[reg], mx[reg]);
        alpha[reg] = __expf(m_run[reg] - mn);
        m_run[reg] = mn;
      }
      float rs[4] = {0.f, 0.f, 0.f, 0.f};
#pragma unroll
      for (int kt = 0; kt < 4; ++kt)
#pragma unroll
        for (int reg = 0; reg < 4; ++reg) {
          float pp = __expf(sc[kt][reg] - m_run[reg]);
          rs[reg] += pp;
          Pb[w][quad * 4 + reg][kt * 16 + l15] = __float2bfloat16(pp);
        }
      for (int d = 1; d < 16; d <<= 1)
#pragma unroll
        for (int reg = 0; reg < 4; ++reg)
          rs[reg] += __shfl_xor(rs[reg], d, 64);
#pragma unroll
      for (int reg = 0; reg < 4; ++reg)
        l_run[reg] = l_run[reg] * alpha[reg] + rs[reg];
#pragma unroll
      for (int dt = 0; dt < 4; ++dt)
#pragma unroll
        for (int reg = 0; reg < 4; ++reg)
          oacc[dt][reg] *= alpha[reg];

      // P (C/D layout) -> A layout via per-wave LDS (no barrier needed)
      short8 pf0 = *(const short8*)&Pb[w][l15][quad * 8];
      short8 pf1 = *(const short8*)&Pb[w][l15][32 + quad * 8];
#pragma unroll
      for (int dt = 0; dt < 4; ++dt) {
        oacc[dt] = mfma16x16x32(pf0, vf0[dt], oacc[dt]);
        oacc[dt] = mfma16x16x32(pf1, vf1[dt], oacc[dt]);
      }
      if (kb < qb) {
#pragma unroll
        for (int kt = 0; kt < 4; ++kt) { kf0[kt] = kn0[kt]; kf1[kt] = kn1[kt]; }
      }
    }

#pragma unroll
    for (int dt = 0; dt < 4; ++dt)
#pragma unroll
      for (int reg = 0; reg < 4; ++reg) {
        int q = qb * 64 + w * 16 + quad * 4 + reg;
        float v = oacc[dt][reg] / l_run[reg];
        O[((size_t)b * SEQ + q) * DM + h * DK + dt * 16 + l15] = __float2bfloat16(v);
      }
  }
}

extern "C" void kernel_launch(void* const* d_in, const int* in_sizes, int n_in,
                              void* d_out, int out_size, void* d_ws, size_t ws_size,
                              hipStream_t stream) {
  const void* x = d_in[0];
  const int* tokpos = (const int*)d_in[1];
  const void* WQ = d_in[2];
  const void* WK = d_in[3];
  const void* WV = d_in[4];
  const void* WO = d_in[5];

  char* ws = (char*)d_ws;
  const size_t MB = 1024 * 1024;
  bf16_t* WT = (bf16_t*)ws;                    // 8 MB (4 x 1024x1024 bf16)
  bf16_t* Qb = (bf16_t*)(ws + 8 * MB);         // 8 MB
  bf16_t* Kb = (bf16_t*)(ws + 16 * MB);        // 8 MB
  bf16_t* VTb = (bf16_t*)(ws + 24 * MB);       // 8 MB, [B*NH, DK, SEQ]
  bf16_t* Xc = (bf16_t*)(ws + 32 * MB);        // 8 MB (canonical bf16 x; reused as Ab)
  bf16_t* Ab = Xc;                             // attn out reuses Xc after last read
  int* flag  = (int*)(ws + 40 * MB);

  dim3 blk(256);
  sniff_dtype<<<1, 64, 0, stream>>>((const unsigned int*)x, flag);
  convert_x<<<4096, blk, 0, stream>>>(x, Xc, flag, (SEQ * 2 * DM) / 4);
  transpose_w<<<dim3(16, 16, 4), blk, 0, stream>>>(WQ, WK, WV, WO, WT, flag);
  gemm_qkv_fused<<<dim3(16, 64), blk, 0, stream>>>(
      Xc, WT + (size_t)0 * DM * DM, WT + (size_t)1 * DM * DM, WT + (size_t)2 * DM * DM,
      Qb, Kb, VTb, tokpos);
  attn_fwd<<<dim3(16, 32), blk, 0, stream>>>(Qb, Kb, VTb, Ab);
  gemm_out<<<dim3(16, 64), blk, 0, stream>>>(Ab, WT + (size_t)3 * DM * DM, d_out, flag);
}